// Round 12
// baseline (46.999 us; speedup 1.0000x reference)
//
#include <hip/hip_runtime.h>

#define D_MODEL   2048
#define F4T       (D_MODEL / 4)        // 512 float4 per token
#define THREADS   512                  // 8 waves
#define NSTRIP    8                    // D_MODEL / (64 lanes * 4 floats)
#define ITERS     2
#define TOK_PER_BLOCK (8 * 2 * ITERS)  // 8 waves x 2 tokens x 2 iters = 32

typedef float f4 __attribute__((ext_vector_type(4)));

// ---- DPP cross-lane add (VALU pipe, not DS pipe) ----
template <int CTRL, int RMASK>
__device__ __forceinline__ float dpp_add(float v) {
    int moved = __builtin_amdgcn_update_dpp(
        0, __builtin_bit_cast(int, v), CTRL, RMASK, 0xf, true);
    return v + __builtin_bit_cast(float, moved);
}
// full-wave sum -> lane 63
__device__ __forceinline__ float red64(float v) {
    v = dpp_add<0x111, 0xf>(v);   // row_shr:1
    v = dpp_add<0x112, 0xf>(v);   // row_shr:2
    v = dpp_add<0x114, 0xf>(v);   // row_shr:4
    v = dpp_add<0x118, 0xf>(v);   // row_shr:8  (lane15 of each row = row sum)
    v = dpp_add<0x142, 0xa>(v);   // row_bcast15 -> rows 1,3: lane31/63 = half sums
    v = dpp_add<0x143, 0xc>(v);   // row_bcast31 -> rows 2,3: lane63 = total
    return v;
}
// per-32-half sums -> lane31 (lanes 0-31), lane63 (lanes 32-63)
__device__ __forceinline__ float red32(float v) {
    v = dpp_add<0x111, 0xf>(v);
    v = dpp_add<0x112, 0xf>(v);
    v = dpp_add<0x114, 0xf>(v);
    v = dpp_add<0x118, 0xf>(v);
    v = dpp_add<0x142, 0xa>(v);
    return v;
}
__device__ __forceinline__ float rdlane(float v, int lane) {
    return __builtin_bit_cast(float,
        __builtin_amdgcn_readlane(__builtin_bit_cast(int, v), lane));
}

// Fused, LDS-staged weights. 2 tokens CONCURRENT per wave (W LDS reads shared:
// 32 ds_read_b128/token) + all reductions on the VALU pipe via DPP (zero
// DS-pipe shuffles). Token A = lanes 0-31, token B = lanes 32-63 for softmax.
__global__ __launch_bounds__(THREADS)
void hypercube_fused_kernel(const float* __restrict__ x,
                            const float* __restrict__ W_to,
                            const float* __restrict__ W_from,
                            const float* __restrict__ log_temp,
                            const float* __restrict__ scale_p,
                            float* __restrict__ out,
                            int n_tokens)
{
    __shared__ f4    sWT[4 * F4T];        // W_to  [k][d] as f4: 32 KB
    __shared__ float sWFT[4 * D_MODEL];   // W_from^T [k][d]:    32 KB

    const int tid  = threadIdx.x;
    const int lane = tid & 63;
    const int wave = tid >> 6;

    const f4* __restrict__ X4  = reinterpret_cast<const f4*>(x);
    const f4* __restrict__ WT4 = reinterpret_cast<const f4*>(W_to);
    const f4* __restrict__ WF4 = reinterpret_cast<const f4*>(W_from);
    f4* __restrict__ O4 = reinterpret_cast<f4*>(out);

    // ---- stage W_to (copy) and W_from (transpose) into LDS ----
#pragma unroll
    for (int j = 0; j < 4; ++j)
        sWT[tid + j * THREADS] = WT4[tid + j * THREADS];
#pragma unroll
    for (int j = 0; j < 4; ++j) {
        const int d = tid + j * THREADS;          // row of W_from
        const f4 w = WF4[d];                      // [k0..k3]
        sWFT[0 * D_MODEL + d] = w.x;              // bank = d%32: conflict-free
        sWFT[1 * D_MODEL + d] = w.y;
        sWFT[2 * D_MODEL + d] = w.z;
        sWFT[3 * D_MODEL + d] = w.w;
    }
    __syncthreads();

    const f4* __restrict__ sWFT4 = reinterpret_cast<const f4*>(sWFT);

    // ---- scalars ----
    float temp = __expf(log_temp[0]);
    temp = fminf(fmaxf(temp, 0.01f), 5.0f);
    const float inv_temp = 1.0f / temp;
    const float scale = scale_p[0];

    const int blockBase = blockIdx.x * TOK_PER_BLOCK;

#pragma unroll 1
    for (int it = 0; it < ITERS; ++it) {
        const int tok0 = blockBase + it * 16 + wave * 2;   // tokens tok0, tok0+1
        if (tok0 >= n_tokens) break;
        const size_t xb0 = (size_t)tok0 * F4T;
        const size_t xb1 = xb0 + F4T;

        // ---- front-load both tokens' x (16 independent dwordx4) ----
        f4 xa[NSTRIP], xc[NSTRIP];
#pragma unroll
        for (int s = 0; s < NSTRIP; ++s)
            xa[s] = X4[xb0 + s * 64 + lane];
#pragma unroll
        for (int s = 0; s < NSTRIP; ++s)
            xc[s] = X4[xb1 + s * 64 + lane];

        // ---- phase 1: shared W_to reads serve BOTH tokens ----
        float z0[4] = {0.f,0.f,0.f,0.f};
        float z1[4] = {0.f,0.f,0.f,0.f};
#pragma unroll
        for (int s = 0; s < NSTRIP; ++s) {
            const int fi = s * 64 + lane;
            const f4 w0 = sWT[0*512 + fi];
            const f4 w1 = sWT[1*512 + fi];
            const f4 w2 = sWT[2*512 + fi];
            const f4 w3 = sWT[3*512 + fi];
            const f4 a = xa[s];
            const f4 b = xc[s];
            z0[0] += a.x*w0.x + a.y*w0.y + a.z*w0.z + a.w*w0.w;
            z0[1] += a.x*w1.x + a.y*w1.y + a.z*w1.z + a.w*w1.w;
            z0[2] += a.x*w2.x + a.y*w2.y + a.z*w2.z + a.w*w2.w;
            z0[3] += a.x*w3.x + a.y*w3.y + a.z*w3.z + a.w*w3.w;
            z1[0] += b.x*w0.x + b.y*w0.y + b.z*w0.z + b.w*w0.w;
            z1[1] += b.x*w1.x + b.y*w1.y + b.z*w1.z + b.w*w1.w;
            z1[2] += b.x*w2.x + b.y*w2.y + b.z*w2.z + b.w*w2.w;
            z1[3] += b.x*w3.x + b.y*w3.y + b.z*w3.z + b.w*w3.w;
        }

        // ---- full-wave DPP reduce of 8 sums (VALU pipe), broadcast via SGPR
        float zA[4], zB[4];
#pragma unroll
        for (int k = 0; k < 4; ++k) {
            zA[k] = rdlane(red64(z0[k]), 63);
            zB[k] = rdlane(red64(z1[k]), 63);
        }

        // ---- softmax: lanes 0-31 -> token A, 32-63 -> token B; vertex lane&15
        // dist>=0 => e in (0,1]: no max-subtraction needed (validated).
        // Each vertex appears twice per 32-half; duplication cancels in ratio.
        const int v = lane & 15;
        const bool isB = lane >= 32;
        float ssum = 0.f;
#pragma unroll
        for (int j = 0; j < 4; ++j) {
            const float zj = isB ? zB[j] : zA[j];
            const float dz = zj - (float)((v >> j) & 1);
            ssum += dz * dz;
        }
        const float e = __expf(-__builtin_amdgcn_sqrtf(ssum) * inv_temp);
        float s0 = e;
        float s1 = ((v >> 0) & 1) ? e : 0.f;
        float s2 = ((v >> 1) & 1) ? e : 0.f;
        float s3 = ((v >> 2) & 1) ? e : 0.f;
        float s4 = ((v >> 3) & 1) ? e : 0.f;
        s0 = red32(s0); s1 = red32(s1); s2 = red32(s2); s3 = red32(s3); s4 = red32(s4);

        const float qsA = scale * __builtin_amdgcn_rcpf(rdlane(s0, 31));
        const float qsB = scale * __builtin_amdgcn_rcpf(rdlane(s0, 63));
        const float qA0 = rdlane(s1, 31) * qsA, qB0 = rdlane(s1, 63) * qsB;
        const float qA1 = rdlane(s2, 31) * qsA, qB1 = rdlane(s2, 63) * qsB;
        const float qA2 = rdlane(s3, 31) * qsA, qB2 = rdlane(s3, 63) * qsB;
        const float qA3 = rdlane(s4, 31) * qsA, qB3 = rdlane(s4, 63) * qsB;

        // ---- phase 2: shared WFT reads serve BOTH tokens ----
#pragma unroll
        for (int s = 0; s < NSTRIP; ++s) {
            const int fi = s * 64 + lane;
            const f4 wk0 = sWFT4[0*512 + fi];
            const f4 wk1 = sWFT4[1*512 + fi];
            const f4 wk2 = sWFT4[2*512 + fi];
            const f4 wk3 = sWFT4[3*512 + fi];
            f4 o0 = xa[s] + qA0*wk0 + qA1*wk1 + qA2*wk2 + qA3*wk3;
            f4 o1 = xc[s] + qB0*wk0 + qB1*wk1 + qB2*wk2 + qB3*wk3;
            __builtin_nontemporal_store(o0, &O4[xb0 + fi]);
            __builtin_nontemporal_store(o1, &O4[xb1 + fi]);
        }
    }
}

extern "C" void kernel_launch(void* const* d_in, const int* in_sizes, int n_in,
                              void* d_out, int out_size, void* d_ws, size_t ws_size,
                              hipStream_t stream) {
    const float* x        = (const float*)d_in[0];
    const float* W_to     = (const float*)d_in[1];
    const float* W_from   = (const float*)d_in[2];
    const float* log_temp = (const float*)d_in[3];
    const float* scale    = (const float*)d_in[4];
    float* out = (float*)d_out;

    const int n_tokens = in_sizes[0] / D_MODEL;      // 16384
    const int blocks = (n_tokens + TOK_PER_BLOCK - 1) / TOK_PER_BLOCK;  // 512
    hypercube_fused_kernel<<<blocks, THREADS, 0, stream>>>(
        x, W_to, W_from, log_temp, scale, out, n_tokens);
}